// Round 1
// baseline (362.592 us; speedup 1.0000x reference)
//
#include <hip/hip_runtime.h>

#define B_DIM 4
#define L_DIM 4096
#define H_DIM 1024
#define U_DIM 1024
#define M_DIM (B_DIM * L_DIM)   // 16384
#define LC 64                    // scan chunk length
#define NCH (L_DIM / LC)         // 64 chunks per sequence

using f32x4  = __attribute__((ext_vector_type(4))) float;
using bf16x8 = __attribute__((ext_vector_type(8))) __bf16;

__device__ inline unsigned short f32_to_bf16(float f) {
  unsigned int u = __float_as_uint(f);
  u += 0x7FFF + ((u >> 16) & 1);   // round-to-nearest-even
  return (unsigned short)(u >> 16);
}

// ---------------- GEMM: C[M,N] = A[M,K] (fp32) * B[N,K]^T (fp32) + bias[N] ----------------
// fp32 global -> bf16 LDS staging -> mfma_f32_16x16x32_bf16, fp32 accum.
#define TM 128
#define TN 128
#define BK 32
#define LDS_STRIDE 40   // 32 + 8 pad: bank stride 20 -> only 2-way conflict (free)

__global__ __launch_bounds__(256) void gemm_bt_bias(
    const float* __restrict__ A, const float* __restrict__ Bm,
    const float* __restrict__ bias, float* __restrict__ C,
    int M, int N, int K)
{
  __shared__ __attribute__((aligned(16))) unsigned short sA[TM * LDS_STRIDE];
  __shared__ __attribute__((aligned(16))) unsigned short sB[TN * LDS_STRIDE];

  const int tid    = threadIdx.x;
  const int lane   = tid & 63;
  const int wave   = tid >> 6;      // 0..3
  const int wm     = wave & 1;      // wave row (64-wide in M)
  const int wn     = wave >> 1;     // wave col (64-wide in N)
  const int frag_m = lane & 15;     // A-row / B-col within 16x16 tile
  const int frag_k = (lane >> 4) * 8;

  const int m0 = blockIdx.y * TM;
  const int n0 = blockIdx.x * TN;

  f32x4 acc[4][4];
  #pragma unroll
  for (int i = 0; i < 4; ++i)
    #pragma unroll
    for (int j = 0; j < 4; ++j)
      acc[i][j] = {0.f, 0.f, 0.f, 0.f};

  for (int k0 = 0; k0 < K; k0 += BK) {
    __syncthreads();   // protect LDS from overwrite while previous tile in use
    #pragma unroll
    for (int i = 0; i < 4; ++i) {
      int q   = tid + i * 256;      // 0..1023
      int row = q >> 3;             // 0..127
      int kq  = (q & 7) * 4;        // 0,4,...,28
      f32x4 va = *(const f32x4*)(A  + (size_t)(m0 + row) * K + k0 + kq);
      f32x4 vb = *(const f32x4*)(Bm + (size_t)(n0 + row) * K + k0 + kq);
      ushort4 ua, ub;
      ua.x = f32_to_bf16(va.x); ua.y = f32_to_bf16(va.y);
      ua.z = f32_to_bf16(va.z); ua.w = f32_to_bf16(va.w);
      ub.x = f32_to_bf16(vb.x); ub.y = f32_to_bf16(vb.y);
      ub.z = f32_to_bf16(vb.z); ub.w = f32_to_bf16(vb.w);
      *(ushort4*)&sA[row * LDS_STRIDE + kq] = ua;
      *(ushort4*)&sB[row * LDS_STRIDE + kq] = ub;
    }
    __syncthreads();

    bf16x8 af[4], bf[4];
    #pragma unroll
    for (int mi = 0; mi < 4; ++mi)
      af[mi] = *(const bf16x8*)&sA[(wm * 64 + mi * 16 + frag_m) * LDS_STRIDE + frag_k];
    #pragma unroll
    for (int ni = 0; ni < 4; ++ni)
      bf[ni] = *(const bf16x8*)&sB[(wn * 64 + ni * 16 + frag_m) * LDS_STRIDE + frag_k];

    #pragma unroll
    for (int mi = 0; mi < 4; ++mi)
      #pragma unroll
      for (int ni = 0; ni < 4; ++ni)
        acc[mi][ni] = __builtin_amdgcn_mfma_f32_16x16x32_bf16(af[mi], bf[ni], acc[mi][ni], 0, 0, 0);
  }

  // Epilogue: D row = (lane>>4)*4 + r, col = lane&15  [m89-verified layout]
  const int r0 = (lane >> 4) * 4;
  #pragma unroll
  for (int ni = 0; ni < 4; ++ni) {
    int col  = n0 + wn * 64 + ni * 16 + frag_m;
    float bv = bias[col];
    #pragma unroll
    for (int mi = 0; mi < 4; ++mi) {
      int rowb = m0 + wm * 64 + mi * 16 + r0;
      #pragma unroll
      for (int r = 0; r < 4; ++r)
        C[(size_t)(rowb + r) * N + col] = acc[mi][ni][r] + bv;
    }
  }
}

// ---------------- params: lam = exp(-exp(nu_log)), gamma = exp(gamma_log), lamLc = lam^LC ----
__global__ void params_kernel(const float* __restrict__ params_log,
                              float* __restrict__ lam, float* __restrict__ gamma,
                              float* __restrict__ lamLc)
{
  int u = blockIdx.x * 256 + threadIdx.x;
  if (u >= U_DIM) return;
  float nu = expf(params_log[u]);
  lam[u]   = expf(-nu);
  gamma[u] = expf(params_log[U_DIM + u]);
  lamLc[u] = expf(-nu * (float)LC);
}

// ---------------- scan phase A: per-chunk local carry ----------------
__global__ void scan_carry(const float* __restrict__ u, const float* __restrict__ lam,
                           float* __restrict__ carry)
{
  int uu = blockIdx.x * 256 + threadIdx.x;
  int c  = blockIdx.y;
  int b  = blockIdx.z;
  float l = lam[uu];
  const float* p = u + (size_t)(b * L_DIM + c * LC) * U_DIM + uu;
  float s = 0.f;
  #pragma unroll 8
  for (int j = 0; j < LC; ++j)
    s = fmaf(s, l, p[(size_t)j * U_DIM]);
  carry[((size_t)b * NCH + c) * U_DIM + uu] = s;
}

// ---------------- scan phase B: sequential scan over chunk carries ----------------
__global__ void scan_prefix(const float* __restrict__ carry, const float* __restrict__ lamLc,
                            float* __restrict__ prefix)
{
  int uu = blockIdx.x * 256 + threadIdx.x;
  int b  = blockIdx.y;
  float lp = lamLc[uu];
  float s = 0.f;
  for (int c = 0; c < NCH; ++c) {
    size_t idx = ((size_t)b * NCH + c) * U_DIM + uu;
    prefix[idx] = s;
    s = s * lp + carry[idx];
  }
}

// ---------------- scan phase C: recompute local scan with carry-in, *gamma, in place ------
__global__ void scan_apply(float* __restrict__ u, const float* __restrict__ lam,
                           const float* __restrict__ gamma, const float* __restrict__ prefix)
{
  int uu = blockIdx.x * 256 + threadIdx.x;
  int c  = blockIdx.y;
  int b  = blockIdx.z;
  float l = lam[uu];
  float g = gamma[uu];
  float s = prefix[((size_t)b * NCH + c) * U_DIM + uu];
  float* p = u + (size_t)(b * L_DIM + c * LC) * U_DIM + uu;
  #pragma unroll 8
  for (int j = 0; j < LC; ++j) {
    float v = p[(size_t)j * U_DIM];
    s = fmaf(s, l, v);
    p[(size_t)j * U_DIM] = s * g;
  }
}

extern "C" void kernel_launch(void* const* d_in, const int* in_sizes, int n_in,
                              void* d_out, int out_size, void* d_ws, size_t ws_size,
                              hipStream_t stream)
{
  const float* inputs     = (const float*)d_in[0];   // (B, L, H)
  const float* Wi         = (const float*)d_in[1];   // (U, H)  == (N,K) row-major
  const float* bi         = (const float*)d_in[2];   // (U,)
  const float* Wo         = (const float*)d_in[3];   // (H, U)  == (N,K) row-major
  const float* bo         = (const float*)d_in[4];   // (H,)
  const float* params_log = (const float*)d_in[5];   // (2, U)
  float* out = (float*)d_out;                        // (B, L, H) fp32

  char* ws = (char*)d_ws;
  float* u_ws   = (float*)(ws);                                   // 64 MB intermediate
  float* carry  = (float*)(ws + 67108864);                        // 1 MB
  float* prefix = (float*)(ws + 67108864 + 1048576);              // 1 MB
  float* lam    = (float*)(ws + 67108864 + 2 * 1048576);          // 4 KB
  float* gamma  = lam + U_DIM;
  float* lamLc  = gamma + U_DIM;

  params_kernel<<<dim3(U_DIM / 256), 256, 0, stream>>>(params_log, lam, gamma, lamLc);

  // GEMM1: u = inputs @ Wi^T + bi   (M=16384, N=U, K=H)
  gemm_bt_bias<<<dim3(U_DIM / TN, M_DIM / TM), 256, 0, stream>>>(
      inputs, Wi, bi, u_ws, M_DIM, U_DIM, H_DIM);

  scan_carry<<<dim3(U_DIM / 256, NCH, B_DIM), 256, 0, stream>>>(u_ws, lam, carry);
  scan_prefix<<<dim3(U_DIM / 256, B_DIM), 256, 0, stream>>>(carry, lamLc, prefix);
  scan_apply<<<dim3(U_DIM / 256, NCH, B_DIM), 256, 0, stream>>>(u_ws, lam, gamma, prefix);

  // GEMM2: out = x @ Wo^T + bo   (M=16384, N=H, K=U)
  gemm_bt_bias<<<dim3(H_DIM / TN, M_DIM / TM), 256, 0, stream>>>(
      u_ws, Wo, bo, out, M_DIM, H_DIM, U_DIM);
}

// Round 2
// 285.453 us; speedup vs baseline: 1.2702x; 1.2702x over previous
//
#include <hip/hip_runtime.h>

#define B_DIM 4
#define L_DIM 4096
#define H_DIM 1024
#define U_DIM 1024
#define M_DIM (B_DIM * L_DIM)   // 16384
#define LC 64                    // scan chunk length
#define NCH (L_DIM / LC)         // 64 chunks per sequence

using f32x4  = __attribute__((ext_vector_type(4))) float;
using bf16x8 = __attribute__((ext_vector_type(8))) __bf16;
using us8    = __attribute__((ext_vector_type(8))) unsigned short;

__device__ inline unsigned short f32_to_bf16(float f) {
  unsigned int u = __float_as_uint(f);
  u += 0x7FFF + ((u >> 16) & 1);   // round-to-nearest-even
  return (unsigned short)(u >> 16);
}

__device__ inline void async_load16(const void* g, void* l) {
  // gfx950: global -> LDS direct, 16B/lane. LDS dest semantics: wave-uniform
  // base + lane*16 — LDS layout must be lane-contiguous (no padding).
  __builtin_amdgcn_global_load_lds(
      (const __attribute__((address_space(1))) void*)g,
      (__attribute__((address_space(3))) void*)l, 16, 0, 0);
}

// ---------------- fused fp32 -> bf16 convert: inputs, Wi, Wo ----------------
#define IN_ELEMS  (M_DIM * H_DIM)          // 16777216
#define WI_ELEMS  (U_DIM * H_DIM)          // 1048576
#define WO_ELEMS  (H_DIM * U_DIM)          // 1048576
#define CVT_TOTAL (IN_ELEMS + WI_ELEMS + WO_ELEMS)

__global__ __launch_bounds__(256) void cvt_all(
    const float* __restrict__ inp, const float* __restrict__ wi,
    const float* __restrict__ wo,
    unsigned short* __restrict__ inp_b, unsigned short* __restrict__ wi_b,
    unsigned short* __restrict__ wo_b)
{
  size_t e = ((size_t)blockIdx.x * 256 + threadIdx.x) * 8;
  if (e >= CVT_TOTAL) return;
  const float* src; unsigned short* dst; size_t off;
  if (e < IN_ELEMS)                 { src = inp; dst = inp_b; off = e; }
  else if (e < IN_ELEMS + WI_ELEMS) { src = wi;  dst = wi_b;  off = e - IN_ELEMS; }
  else                              { src = wo;  dst = wo_b;  off = e - IN_ELEMS - WI_ELEMS; }
  f32x4 a = *(const f32x4*)(src + off);
  f32x4 b = *(const f32x4*)(src + off + 4);
  us8 r;
  r[0] = f32_to_bf16(a.x); r[1] = f32_to_bf16(a.y);
  r[2] = f32_to_bf16(a.z); r[3] = f32_to_bf16(a.w);
  r[4] = f32_to_bf16(b.x); r[5] = f32_to_bf16(b.y);
  r[6] = f32_to_bf16(b.z); r[7] = f32_to_bf16(b.w);
  *(us8*)(dst + off) = r;
}

// ---------------- GEMM: C[M,N] = A[M,K](bf16) * B[N,K]^T(bf16) + bias[N] ----
// m97 structure: 128x128 tile, BK=32, global_load_lds width=16, 4 waves 2x2,
// each wave 4x4 of mfma_f32_16x16x32_bf16.
#define TM 128
#define TN 128
#define BK 32

__global__ __launch_bounds__(256) void gemm_bt_bias(
    const unsigned short* __restrict__ A, const unsigned short* __restrict__ Bm,
    const float* __restrict__ bias, float* __restrict__ C,
    int M, int N, int K)
{
  // unpadded: 128 rows x 32 bf16 = 64 B/row, 8 KB per tile
  __shared__ __attribute__((aligned(16))) unsigned short sA[TM * BK];
  __shared__ __attribute__((aligned(16))) unsigned short sB[TN * BK];

  const int tid    = threadIdx.x;
  const int lane   = tid & 63;
  const int wave   = tid >> 6;      // 0..3
  const int wm     = wave & 1;
  const int wn     = wave >> 1;
  const int frag_m = lane & 15;
  const int frag_kb = (lane >> 4) * 16;   // byte offset of 8-bf16 k-group

  const int m0 = blockIdx.y * TM;
  const int n0 = blockIdx.x * TN;

  const char* Ab = (const char*)A;
  const char* Bb = (const char*)Bm;
  const size_t rowbytes = (size_t)K * 2;

  // staging geometry: byte offset o in [0,8192), row = o>>6, colbyte = o&63
  const int o0 = tid * 16;          // issue 0
  const int o1 = o0 + 4096;         // issue 1
  const int r0s = o0 >> 6, c0s = o0 & 63;
  const int r1s = o1 >> 6, c1s = o1 & 63;

  f32x4 acc[4][4];
  #pragma unroll
  for (int i = 0; i < 4; ++i)
    #pragma unroll
    for (int j = 0; j < 4; ++j)
      acc[i][j] = {0.f, 0.f, 0.f, 0.f};

  for (int k0 = 0; k0 < K; k0 += BK) {
    __syncthreads();   // previous tile's ds_reads complete
    const size_t kb = (size_t)k0 * 2;
    async_load16(Ab + (size_t)(m0 + r0s) * rowbytes + kb + c0s, (char*)sA + o0);
    async_load16(Ab + (size_t)(m0 + r1s) * rowbytes + kb + c1s, (char*)sA + o1);
    async_load16(Bb + (size_t)(n0 + r0s) * rowbytes + kb + c0s, (char*)sB + o0);
    async_load16(Bb + (size_t)(n0 + r1s) * rowbytes + kb + c1s, (char*)sB + o1);
    __syncthreads();   // drains vmcnt -> LDS valid

    bf16x8 af[4], bf[4];
    #pragma unroll
    for (int mi = 0; mi < 4; ++mi)
      af[mi] = *(const bf16x8*)((const char*)sA + (wm * 64 + mi * 16 + frag_m) * 64 + frag_kb);
    #pragma unroll
    for (int ni = 0; ni < 4; ++ni)
      bf[ni] = *(const bf16x8*)((const char*)sB + (wn * 64 + ni * 16 + frag_m) * 64 + frag_kb);

    #pragma unroll
    for (int mi = 0; mi < 4; ++mi)
      #pragma unroll
      for (int ni = 0; ni < 4; ++ni)
        acc[mi][ni] = __builtin_amdgcn_mfma_f32_16x16x32_bf16(af[mi], bf[ni], acc[mi][ni], 0, 0, 0);
  }

  // Epilogue: D row = (lane>>4)*4 + r, col = lane&15  [m89-verified layout]
  const int rr0 = (lane >> 4) * 4;
  #pragma unroll
  for (int ni = 0; ni < 4; ++ni) {
    int col  = n0 + wn * 64 + ni * 16 + frag_m;
    float bv = bias[col];
    #pragma unroll
    for (int mi = 0; mi < 4; ++mi) {
      int rowb = m0 + wm * 64 + mi * 16 + rr0;
      #pragma unroll
      for (int r = 0; r < 4; ++r)
        C[(size_t)(rowb + r) * N + col] = acc[mi][ni][r] + bv;
    }
  }
}

// ---------------- scan phase A: per-chunk local carry (params inlined) -------
__global__ __launch_bounds__(256) void scan_carry(
    const float* __restrict__ u, const float* __restrict__ params_log,
    float* __restrict__ carry)
{
  int uu = blockIdx.x * 256 + threadIdx.x;
  int c  = blockIdx.y;
  int b  = blockIdx.z;
  float l = expf(-expf(params_log[uu]));
  const float* p = u + (size_t)(b * L_DIM + c * LC) * U_DIM + uu;
  float s = 0.f;
  #pragma unroll 8
  for (int j = 0; j < LC; ++j)
    s = fmaf(s, l, p[(size_t)j * U_DIM]);
  carry[((size_t)b * NCH + c) * U_DIM + uu] = s;
}

// ---------------- scan phase B: prefix over chunk carries, loads batched -----
__global__ __launch_bounds__(256) void scan_prefix(
    const float* __restrict__ carry, const float* __restrict__ params_log,
    float* __restrict__ prefix)
{
  int t  = blockIdx.x * 256 + threadIdx.x;   // over B*U
  int b  = t >> 10;          // U_DIM == 1024
  int uu = t & (U_DIM - 1);
  float lp = expf(-expf(params_log[uu]) * (float)LC);
  const float* cp = carry  + (size_t)b * NCH * U_DIM + uu;
  float*       pp = prefix + (size_t)b * NCH * U_DIM + uu;
  float vals[NCH];
  #pragma unroll
  for (int c = 0; c < NCH; ++c)
    vals[c] = cp[(size_t)c * U_DIM];          // independent loads, all in flight
  float s = 0.f;
  #pragma unroll
  for (int c = 0; c < NCH; ++c) {
    pp[(size_t)c * U_DIM] = s;
    s = fmaf(s, lp, vals[c]);
  }
}

// ---------------- scan phase C: local scan + carry-in, *gamma, emit bf16 -----
__global__ __launch_bounds__(256) void scan_apply(
    const float* __restrict__ u, const float* __restrict__ params_log,
    const float* __restrict__ prefix, unsigned short* __restrict__ x_b)
{
  int uu = blockIdx.x * 256 + threadIdx.x;
  int c  = blockIdx.y;
  int b  = blockIdx.z;
  float l = expf(-expf(params_log[uu]));
  float g = expf(params_log[U_DIM + uu]);
  float s = prefix[((size_t)b * NCH + c) * U_DIM + uu];
  const float* p = u + (size_t)(b * L_DIM + c * LC) * U_DIM + uu;
  unsigned short* q = x_b + (size_t)(b * L_DIM + c * LC) * U_DIM + uu;
  #pragma unroll 8
  for (int j = 0; j < LC; ++j) {
    s = fmaf(s, l, p[(size_t)j * U_DIM]);
    q[(size_t)j * U_DIM] = f32_to_bf16(s * g);
  }
}

extern "C" void kernel_launch(void* const* d_in, const int* in_sizes, int n_in,
                              void* d_out, int out_size, void* d_ws, size_t ws_size,
                              hipStream_t stream)
{
  const float* inputs     = (const float*)d_in[0];   // (B, L, H)
  const float* Wi         = (const float*)d_in[1];   // (U, H)
  const float* bi         = (const float*)d_in[2];   // (U,)
  const float* Wo         = (const float*)d_in[3];   // (H, U)
  const float* bo         = (const float*)d_in[4];   // (H,)
  const float* params_log = (const float*)d_in[5];   // (2, U)
  float* out = (float*)d_out;                        // (B, L, H) fp32

  char* ws = (char*)d_ws;
  float*          u_ws   = (float*)(ws);                          // 64 MB fp32 u
  unsigned short* x_b    = (unsigned short*)(ws + (64u << 20));   // 32 MB bf16 x
  unsigned short* in_b   = (unsigned short*)(ws + (96u << 20));   // 32 MB bf16 inputs
  unsigned short* wi_b   = (unsigned short*)(ws + (128u << 20));  //  2 MB bf16 Wi
  unsigned short* wo_b   = (unsigned short*)(ws + (130u << 20));  //  2 MB bf16 Wo
  float*          carry  = (float*)(ws + (132u << 20));           //  1 MB
  float*          prefix = (float*)(ws + (133u << 20));           //  1 MB

  cvt_all<<<dim3((CVT_TOTAL / 8 + 255) / 256), 256, 0, stream>>>(
      inputs, Wi, Wo, in_b, wi_b, wo_b);

  // GEMM1: u = inputs @ Wi^T + bi   (M=16384, N=U, K=H)
  gemm_bt_bias<<<dim3(U_DIM / TN, M_DIM / TM), 256, 0, stream>>>(
      in_b, wi_b, bi, u_ws, M_DIM, U_DIM, H_DIM);

  scan_carry <<<dim3(U_DIM / 256, NCH, B_DIM), 256, 0, stream>>>(u_ws, params_log, carry);
  scan_prefix<<<dim3(B_DIM * U_DIM / 256),     256, 0, stream>>>(carry, params_log, prefix);
  scan_apply <<<dim3(U_DIM / 256, NCH, B_DIM), 256, 0, stream>>>(u_ws, params_log, prefix, x_b);

  // GEMM2: out = x @ Wo^T + bo   (M=16384, N=H, K=U)
  gemm_bt_bias<<<dim3(H_DIM / TN, M_DIM / TM), 256, 0, stream>>>(
      x_b, wo_b, bo, out, M_DIM, H_DIM, U_DIM);
}

// Round 3
// 252.223 us; speedup vs baseline: 1.4376x; 1.1318x over previous
//
#include <hip/hip_runtime.h>

#define B_DIM 4
#define L_DIM 4096
#define H_DIM 1024
#define U_DIM 1024
#define M_DIM (B_DIM * L_DIM)   // 16384
#define LC 64                    // scan chunk length
#define NCH (L_DIM / LC)         // 64 chunks per sequence

using f32x4  = __attribute__((ext_vector_type(4))) float;
using bf16x8 = __attribute__((ext_vector_type(8))) __bf16;
using us8    = __attribute__((ext_vector_type(8))) unsigned short;

__device__ inline unsigned short f32_to_bf16(float f) {
  unsigned int u = __float_as_uint(f);
  u += 0x7FFF + ((u >> 16) & 1);   // round-to-nearest-even
  return (unsigned short)(u >> 16);
}
__device__ inline float bf16_to_f32(unsigned short v) {
  return __uint_as_float((unsigned int)v << 16);
}

__device__ inline void async_load16(const void* g, void* l) {
  // gfx950 global->LDS direct, 16B/lane; LDS dest = wave-uniform base + lane*16.
  __builtin_amdgcn_global_load_lds(
      (const __attribute__((address_space(1))) void*)g,
      (__attribute__((address_space(3))) void*)l, 16, 0, 0);
}

// ---------------- fused fp32 -> bf16 convert: inputs, Wi, Wo ----------------
#define IN_ELEMS  (M_DIM * H_DIM)          // 16777216
#define WI_ELEMS  (U_DIM * H_DIM)          // 1048576
#define WO_ELEMS  (H_DIM * U_DIM)          // 1048576
#define CVT_TOTAL (IN_ELEMS + WI_ELEMS + WO_ELEMS)

__global__ __launch_bounds__(256) void cvt_all(
    const float* __restrict__ inp, const float* __restrict__ wi,
    const float* __restrict__ wo,
    unsigned short* __restrict__ inp_b, unsigned short* __restrict__ wi_b,
    unsigned short* __restrict__ wo_b)
{
  size_t e = ((size_t)blockIdx.x * 256 + threadIdx.x) * 8;
  if (e >= CVT_TOTAL) return;
  const float* src; unsigned short* dst; size_t off;
  if (e < IN_ELEMS)                 { src = inp; dst = inp_b; off = e; }
  else if (e < IN_ELEMS + WI_ELEMS) { src = wi;  dst = wi_b;  off = e - IN_ELEMS; }
  else                              { src = wo;  dst = wo_b;  off = e - IN_ELEMS - WI_ELEMS; }
  f32x4 a = *(const f32x4*)(src + off);
  f32x4 b = *(const f32x4*)(src + off + 4);
  us8 r;
  r[0] = f32_to_bf16(a.x); r[1] = f32_to_bf16(a.y);
  r[2] = f32_to_bf16(a.z); r[3] = f32_to_bf16(a.w);
  r[4] = f32_to_bf16(b.x); r[5] = f32_to_bf16(b.y);
  r[6] = f32_to_bf16(b.z); r[7] = f32_to_bf16(b.w);
  *(us8*)(dst + off) = r;
}

// ---------------- GEMM: C[M,N] = A[M,K](bf16) * B[N,K]^T(bf16) + bias[N] ----
// m97 structure + BK=64 (two BK=32 sub-tiles per barrier pair) + XCD swizzle.
#define TM 128
#define TN 128

template <typename OUT>
__global__ __launch_bounds__(256) void gemm_bt_bias(
    const unsigned short* __restrict__ A, const unsigned short* __restrict__ Bm,
    const float* __restrict__ bias, OUT* __restrict__ C,
    int M, int N, int K)
{
  // two k-halves, each 128 rows x 32 bf16 = 64B rows, 8KB -> 32KB total
  __shared__ __attribute__((aligned(16))) unsigned short sA[2][TM * 32];
  __shared__ __attribute__((aligned(16))) unsigned short sB[2][TN * 32];

  const int tid    = threadIdx.x;
  const int lane   = tid & 63;
  const int wave   = tid >> 6;
  const int wm     = wave & 1;
  const int wn     = wave >> 1;
  const int frag_m = lane & 15;
  const int frag_kb = (lane >> 4) * 16;   // byte offset of 8-bf16 k-group

  // XCD-aware swizzle: dispatch index p -> XCD p%8. Give each XCD a 16-tall
  // M-slab (all N-tiles): A-slab 4MB + B 2MB ~ L2-resident, A fetched once.
  const int p    = blockIdx.y * gridDim.x + blockIdx.x;
  const int xcd  = p & 7;
  const int j    = p >> 3;
  const int slab = gridDim.y >> 3;              // 16 for M=16384
  const int by   = xcd * slab + (j % slab);
  const int bx   = j / slab;

  const int m0 = by * TM;
  const int n0 = bx * TN;

  const char* Ab = (const char*)A;
  const char* Bb = (const char*)Bm;
  const size_t rowbytes = (size_t)K * 2;

  // staging geometry: byte offset o in [0,8192) per half; row = o>>6, col = o&63
  const int o0 = tid * 16;
  const int o1 = o0 + 4096;
  const int r0s = o0 >> 6, c0s = o0 & 63;
  const int r1s = o1 >> 6, c1s = o1 & 63;

  f32x4 acc[4][4];
  #pragma unroll
  for (int i = 0; i < 4; ++i)
    #pragma unroll
    for (int jj = 0; jj < 4; ++jj)
      acc[i][jj] = {0.f, 0.f, 0.f, 0.f};

  for (int k0 = 0; k0 < K; k0 += 64) {
    __syncthreads();
    #pragma unroll
    for (int h = 0; h < 2; ++h) {
      const size_t kb = (size_t)(k0 + h * 32) * 2;
      async_load16(Ab + (size_t)(m0 + r0s) * rowbytes + kb + c0s, (char*)sA[h] + o0);
      async_load16(Ab + (size_t)(m0 + r1s) * rowbytes + kb + c1s, (char*)sA[h] + o1);
      async_load16(Bb + (size_t)(n0 + r0s) * rowbytes + kb + c0s, (char*)sB[h] + o0);
      async_load16(Bb + (size_t)(n0 + r1s) * rowbytes + kb + c1s, (char*)sB[h] + o1);
    }
    __syncthreads();

    #pragma unroll
    for (int h = 0; h < 2; ++h) {
      bf16x8 af[4], bf[4];
      #pragma unroll
      for (int mi = 0; mi < 4; ++mi)
        af[mi] = *(const bf16x8*)((const char*)sA[h] + (wm * 64 + mi * 16 + frag_m) * 64 + frag_kb);
      #pragma unroll
      for (int ni = 0; ni < 4; ++ni)
        bf[ni] = *(const bf16x8*)((const char*)sB[h] + (wn * 64 + ni * 16 + frag_m) * 64 + frag_kb);

      #pragma unroll
      for (int mi = 0; mi < 4; ++mi)
        #pragma unroll
        for (int ni = 0; ni < 4; ++ni)
          acc[mi][ni] = __builtin_amdgcn_mfma_f32_16x16x32_bf16(af[mi], bf[ni], acc[mi][ni], 0, 0, 0);
    }
  }

  // Epilogue: D row = (lane>>4)*4 + r, col = lane&15  [m89-verified layout]
  const int rr0 = (lane >> 4) * 4;
  #pragma unroll
  for (int ni = 0; ni < 4; ++ni) {
    int col  = n0 + wn * 64 + ni * 16 + frag_m;
    float bv = bias[col];
    #pragma unroll
    for (int mi = 0; mi < 4; ++mi) {
      int rowb = m0 + wm * 64 + mi * 16 + rr0;
      #pragma unroll
      for (int r = 0; r < 4; ++r) {
        float v = acc[mi][ni][r] + bv;
        if constexpr (sizeof(OUT) == 2)
          C[(size_t)(rowb + r) * N + col] = (OUT)f32_to_bf16(v);
        else
          C[(size_t)(rowb + r) * N + col] = (OUT)v;
      }
    }
  }
}

// ---------------- scan phase A: per-chunk local carry (bf16 u) ---------------
__global__ __launch_bounds__(256) void scan_carry(
    const unsigned short* __restrict__ u, const float* __restrict__ params_log,
    float* __restrict__ carry)
{
  int uu = blockIdx.x * 256 + threadIdx.x;
  int c  = blockIdx.y;
  int b  = blockIdx.z;
  float l = expf(-expf(params_log[uu]));
  const unsigned short* p = u + (size_t)(b * L_DIM + c * LC) * U_DIM + uu;
  float s = 0.f;
  #pragma unroll 8
  for (int j = 0; j < LC; ++j)
    s = fmaf(s, l, bf16_to_f32(p[(size_t)j * U_DIM]));
  carry[((size_t)b * NCH + c) * U_DIM + uu] = s;
}

// ---------------- scan phase B: prefix over chunk carries --------------------
__global__ __launch_bounds__(256) void scan_prefix(
    const float* __restrict__ carry, const float* __restrict__ params_log,
    float* __restrict__ prefix)
{
  int t  = blockIdx.x * 256 + threadIdx.x;   // over B*U
  int b  = t >> 10;
  int uu = t & (U_DIM - 1);
  float lp = expf(-expf(params_log[uu]) * (float)LC);
  const float* cp = carry  + (size_t)b * NCH * U_DIM + uu;
  float*       pp = prefix + (size_t)b * NCH * U_DIM + uu;
  float vals[NCH];
  #pragma unroll
  for (int c = 0; c < NCH; ++c)
    vals[c] = cp[(size_t)c * U_DIM];
  float s = 0.f;
  #pragma unroll
  for (int c = 0; c < NCH; ++c) {
    pp[(size_t)c * U_DIM] = s;
    s = fmaf(s, lp, vals[c]);
  }
}

// ---------------- scan phase C: local scan + carry-in, *gamma, bf16 out ------
__global__ __launch_bounds__(256) void scan_apply(
    const unsigned short* __restrict__ u, const float* __restrict__ params_log,
    const float* __restrict__ prefix, unsigned short* __restrict__ x_b)
{
  int uu = blockIdx.x * 256 + threadIdx.x;
  int c  = blockIdx.y;
  int b  = blockIdx.z;
  float l = expf(-expf(params_log[uu]));
  float g = expf(params_log[U_DIM + uu]);
  float s = prefix[((size_t)b * NCH + c) * U_DIM + uu];
  const unsigned short* p = u + (size_t)(b * L_DIM + c * LC) * U_DIM + uu;
  unsigned short* q = x_b + (size_t)(b * L_DIM + c * LC) * U_DIM + uu;
  #pragma unroll 8
  for (int j = 0; j < LC; ++j) {
    s = fmaf(s, l, bf16_to_f32(p[(size_t)j * U_DIM]));
    q[(size_t)j * U_DIM] = f32_to_bf16(s * g);
  }
}

extern "C" void kernel_launch(void* const* d_in, const int* in_sizes, int n_in,
                              void* d_out, int out_size, void* d_ws, size_t ws_size,
                              hipStream_t stream)
{
  const float* inputs     = (const float*)d_in[0];   // (B, L, H)
  const float* Wi         = (const float*)d_in[1];   // (U, H)
  const float* bi         = (const float*)d_in[2];   // (U,)
  const float* Wo         = (const float*)d_in[3];   // (H, U)
  const float* bo         = (const float*)d_in[4];   // (H,)
  const float* params_log = (const float*)d_in[5];   // (2, U)
  float* out = (float*)d_out;                        // (B, L, H) fp32

  char* ws = (char*)d_ws;
  unsigned short* u_b    = (unsigned short*)(ws);                 // 32 MB bf16 u
  unsigned short* x_b    = (unsigned short*)(ws + (32u << 20));   // 32 MB bf16 x
  unsigned short* in_b   = (unsigned short*)(ws + (64u << 20));   // 32 MB bf16 inputs
  unsigned short* wi_b   = (unsigned short*)(ws + (96u << 20));   //  2 MB bf16 Wi
  unsigned short* wo_b   = (unsigned short*)(ws + (98u << 20));   //  2 MB bf16 Wo
  float*          carry  = (float*)(ws + (100u << 20));           //  1 MB
  float*          prefix = (float*)(ws + (101u << 20));           //  1 MB

  cvt_all<<<dim3((CVT_TOTAL / 8 + 255) / 256), 256, 0, stream>>>(
      inputs, Wi, Wo, in_b, wi_b, wo_b);

  // GEMM1: u = inputs @ Wi^T + bi   (M=16384, N=U, K=H) -> bf16
  gemm_bt_bias<unsigned short><<<dim3(U_DIM / TN, M_DIM / TM), 256, 0, stream>>>(
      in_b, wi_b, bi, u_b, M_DIM, U_DIM, H_DIM);

  scan_carry <<<dim3(U_DIM / 256, NCH, B_DIM), 256, 0, stream>>>(u_b, params_log, carry);
  scan_prefix<<<dim3(B_DIM * U_DIM / 256),     256, 0, stream>>>(carry, params_log, prefix);
  scan_apply <<<dim3(U_DIM / 256, NCH, B_DIM), 256, 0, stream>>>(u_b, params_log, prefix, x_b);

  // GEMM2: out = x @ Wo^T + bo   (M=16384, N=H, K=U) -> fp32
  gemm_bt_bias<float><<<dim3(H_DIM / TN, M_DIM / TM), 256, 0, stream>>>(
      x_b, wo_b, bo, out, M_DIM, H_DIM, U_DIM);
}